// Round 9
// baseline (273.559 us; speedup 1.0000x reference)
//
#include <hip/hip_runtime.h>
#include <math.h>

#define ALPHA 50.0f
#define EPS 1e-12f

constexpr int N = 64, C = 128, P = 4096, K = 64;
constexpr int NCH2 = 8;           // partial groups (one per block per n)

typedef short short8_t __attribute__((ext_vector_type(8)));
typedef short short4_t __attribute__((ext_vector_type(4)));
typedef float f4 __attribute__((ext_vector_type(4)));
typedef unsigned int u32x4 __attribute__((ext_vector_type(4)));
typedef unsigned int u32x2 __attribute__((ext_vector_type(2)));

__device__ __forceinline__ unsigned short f2bf(float f) {
    union { float f; unsigned u; } v; v.f = f;
    unsigned r = (v.u + 0x7FFFu + ((v.u >> 16) & 1u)) >> 16;   // RNE
    return (unsigned short)r;
}

// packed f32x2 -> bf16x2 (RNE), single VALU op
__device__ __forceinline__ unsigned cvtpk(float lo, float hi) {
    unsigned r;
    asm("v_cvt_pk_bf16_f32 %0, %1, %2" : "=v"(r) : "v"(lo), "v"(hi));
    return r;
}

// __syncthreads() minus the vmcnt(0) drain: LDS-visibility barrier only.
__device__ __forceinline__ void bar_lds() {
    asm volatile("s_waitcnt lgkmcnt(0)" ::: "memory");
    __builtin_amdgcn_s_barrier();
}

// ---------------------------------------------------------------------------
// Prep: wnT[k][c] = bf16(W[c][k]/max(||W[:,k]||,eps)), one block; also zeroes
// the ss2 accumulator. Removes 512x 64KB W reads + 3 barriers from k_fused.
// ---------------------------------------------------------------------------
__global__ __launch_bounds__(256) void k_prep(
    const float* __restrict__ W, unsigned short* __restrict__ wnT,
    float* __restrict__ ss2acc)
{
    __shared__ float Wl[C * 65];
    __shared__ float red[256];
    __shared__ float cinv[K];
    const int tid = threadIdx.x;
    if (tid < K) ss2acc[tid] = 0.f;
    for (int idx = tid; idx < C * K; idx += 256) {
        int c = idx >> 6, k = idx & 63;
        Wl[c * 65 + k] = W[idx];
    }
    __syncthreads();
    {   // column sum-of-squares, tree order identical to rd8's prologue
        const int k = tid & 63, part = tid >> 6;
        float s = 0.f;
        #pragma unroll
        for (int i = 0; i < 32; ++i) {
            float v = Wl[(part * 32 + i) * 65 + k];
            s = fmaf(v, v, s);
        }
        red[tid] = s;
    }
    __syncthreads();
    if (tid < K)
        cinv[tid] = 1.0f / fmaxf(
            sqrtf(red[tid] + red[64 + tid] + red[128 + tid] + red[192 + tid]), EPS);
    __syncthreads();
    for (int idx = tid; idx < K * C; idx += 256) {
        int k = idx >> 7, c = idx & 127;
        wnT[idx] = f2bf(Wl[c * 65 + k] * cinv[k]);
    }
}

// ---------------------------------------------------------------------------
// Fused, wave-autonomous (rd8 skeleton) + stream fixes:
//  - prologue: af frags from L2-hot bf16 wnT (no W read, no barriers)
//  - 2-deep x prefetch (vA/vB; issue ch+2 when buffer dies)
//  - logits staged in LDS (lgs) and stored cooperatively post-B1:
//    4 x float4/thread, 4 rows x 256 B full lines per instruction, no NT
// ---------------------------------------------------------------------------
__global__ __launch_bounds__(256, 2) void k_fused(
    const float* __restrict__ x, const unsigned short* __restrict__ wnT,
    const float* __restrict__ bias, float* __restrict__ logits,
    float* __restrict__ vlad_part, float* __restrict__ Spart)
{
    __shared__ __align__(16) char smem[64512];
    unsigned short* xsT  = (unsigned short*)smem;            // [4 w][16 px][136 c] bf16, 17408 B
    unsigned short* xsN  = (unsigned short*)(smem + 17408);  // [128 c][76 px] bf16, 19456 B
    unsigned short* sa2s = (unsigned short*)(smem + 36864);  // [64 k][72 px] bf16, 9216 B
    float*          lgs  = (float*)(smem + 46080);           // [64 k][68 px] f32, 17408 B
    float*          Sb2  = (float*)(smem + 63488);           // [4][64] f32, 1024 B

    const int tid  = threadIdx.x;
    const int n    = blockIdx.x >> 3;
    const int blk8 = blockIdx.x & 7;
    const int pbase = blk8 * 512;

    const int w = tid >> 6, lane = tid & 63;
    const int q = lane >> 4, l15 = lane & 15;
    const int c2 = lane >> 2, px4 = lane & 3;    // staging roles

    // per-lane global base: c = 8*c2 + j rows, px = 16w + 4*px4 (+i)
    const float* xw = x + (size_t)n * C * P + pbase + 16 * w + 4 * px4 + (size_t)(8 * c2) * P;
    float4 vA[8], vB[8];
    short8_t af[4][4];      // A-frags for ALL 4 k-tiles x 4 c-steps (64 VGPR)
    float bzv[16];

    // ---- prologue: no barriers. 2-deep x prefetch + wnT frags + bias ----
    #pragma unroll
    for (int j = 0; j < 8; ++j) vA[j] = *(const float4*)&xw[(size_t)j * P];
    #pragma unroll
    for (int j = 0; j < 8; ++j) vB[j] = *(const float4*)&xw[(size_t)j * P + 64];
    #pragma unroll
    for (int kt = 0; kt < 4; ++kt) {
        #pragma unroll
        for (int s = 0; s < 4; ++s)
            af[kt][s] = *(const short8_t*)&wnT[(16 * kt + l15) * 128 + s * 32 + 8 * q];
        #pragma unroll
        for (int r = 0; r < 4; ++r)
            bzv[4 * kt + r] = bias[16 * kt + 4 * q + r] * ALPHA;
    }

    f4 acc2[8];
    #pragma unroll
    for (int ct = 0; ct < 8; ++ct) acc2[ct] = (f4){0.f, 0.f, 0.f, 0.f};
    float Sreg[16];
    #pragma unroll
    for (int i = 0; i < 16; ++i) Sreg[i] = 0.f;

    unsigned short* xsTw = xsT + w * 2176;   // own slice, 16 rows x 136 shorts

    for (int ch2 = 0; ch2 < 8; ch2 += 2) {
        #pragma unroll
        for (int ph = 0; ph < 2; ++ph) {
            const int ch = ch2 + ph;
            float4 (&vcur)[8] = ph ? vB : vA;
            const float* vf = (const float*)vcur;

            // ---- in-wave ssq + invs (no LDS) ----
            float pss[4] = {0.f, 0.f, 0.f, 0.f};
            #pragma unroll
            for (int j = 0; j < 8; ++j)
                #pragma unroll
                for (int i = 0; i < 4; ++i)
                    pss[i] = fmaf(vf[j * 4 + i], vf[j * 4 + i], pss[i]);
            #pragma unroll
            for (int i = 0; i < 4; ++i) {
                pss[i] += __shfl_xor(pss[i], 4);
                pss[i] += __shfl_xor(pss[i], 8);
                pss[i] += __shfl_xor(pss[i], 16);
                pss[i] += __shfl_xor(pss[i], 32);
            }
            float iv4[4];
            #pragma unroll
            for (int i = 0; i < 4; ++i) iv4[i] = 1.0f / fmaxf(sqrtf(pss[i]), EPS);

            // ---- stage own xsT slice (XOR-swizzled) + shared xsN ----
            #pragma unroll
            for (int i = 0; i < 4; ++i) {
                u32x4 t;
                #pragma unroll
                for (int jj = 0; jj < 4; ++jj)
                    t[jj] = cvtpk(vf[(2 * jj) * 4 + i], vf[(2 * jj + 1) * 4 + i]);
                const int row = 4 * px4 + i;
                *(u32x4*)&xsTw[row * 136 + 8 * (c2 ^ (row & 7))] = t;
            }
            #pragma unroll
            for (int j = 0; j < 8; ++j) {
                u32x2 t2;
                t2[0] = cvtpk(vf[j * 4 + 0], vf[j * 4 + 1]);
                t2[1] = cvtpk(vf[j * 4 + 2], vf[j * 4 + 3]);
                *(u32x2*)&xsN[(8 * c2 + j) * 76 + 16 * w + 4 * px4] = t2;
            }
            // ---- vcur dead: issue ch+2 loads (2 chunks of latency cover) ----
            if (ch + 2 < 8) {
                #pragma unroll
                for (int j = 0; j < 8; ++j)
                    vcur[j] = *(const float4*)&xw[(size_t)j * P + (ch + 2) * 64];
            }
            asm volatile("s_waitcnt lgkmcnt(0)" ::: "memory");  // own-slice w->r order
            __builtin_amdgcn_sched_barrier(0);                  // rule-18 hardening

            // ---- GEMM1 from own slice: 4 B-reads total, A in regs ----
            f4 acc1[4];
            #pragma unroll
            for (int t = 0; t < 4; ++t) acc1[t] = (f4){0.f, 0.f, 0.f, 0.f};
            __builtin_amdgcn_s_setprio(1);
            #pragma unroll
            for (int s = 0; s < 4; ++s) {
                short8_t bf = *(const short8_t*)&xsTw[l15 * 136 + 8 * ((4 * s + q) ^ (l15 & 7))];
                #pragma unroll
                for (int kt = 0; kt < 4; ++kt)
                    acc1[kt] = __builtin_amdgcn_mfma_f32_16x16x32_bf16(af[kt][s], bf, acc1[kt], 0, 0, 0);
            }
            __builtin_amdgcn_s_setprio(0);

            // ---- in-register softmax; logits -> lgs (LDS), not global ----
            const float s0 = __shfl(iv4[0], l15 >> 2);
            const float s1 = __shfl(iv4[1], l15 >> 2);
            const float s2 = __shfl(iv4[2], l15 >> 2);
            const float s3 = __shfl(iv4[3], l15 >> 2);
            const int li = l15 & 3;
            const float myiv = (li == 0) ? s0 : (li == 1) ? s1 : (li == 2) ? s2 : s3;

            float ev[16];
            float dl = 0.f;
            #pragma unroll
            for (int kt = 0; kt < 4; ++kt)
                #pragma unroll
                for (int r = 0; r < 4; ++r) {
                    const float lv = acc1[kt][r] * myiv;
                    lgs[(16 * kt + 4 * q + r) * 68 + 16 * w + l15] = lv;
                    const float e = __expf(fmaf(lv, ALPHA, bzv[4 * kt + r]));
                    ev[4 * kt + r] = e;
                    dl += e;
                }
            dl += __shfl_xor(dl, 16);
            dl += __shfl_xor(dl, 32);
            const float rf = 1.0f / dl;
            const float sc = rf * myiv;
            #pragma unroll
            for (int kt = 0; kt < 4; ++kt)
                #pragma unroll
                for (int r = 0; r < 4; ++r) {
                    const float e = ev[4 * kt + r];
                    Sreg[4 * kt + r] += e * rf;
                    sa2s[(16 * kt + 4 * q + r) * 72 + 16 * w + l15] = f2bf(e * sc);
                }
            bar_lds();                          // B1: sa2s + xsN + lgs visible

            // ---- cooperative logits store: full-line float4 writes ----
            {
                float* lgp = logits + (size_t)n * K * P + pbase + ch * 64;
                #pragma unroll
                for (int jj = 0; jj < 4; ++jj) {
                    const int k = 16 * w + 4 * jj + (lane >> 4);
                    const f4 t = *(const f4*)&lgs[k * 68 + 4 * (lane & 15)];
                    *(f4*)&lgp[(size_t)k * P + 4 * (lane & 15)] = t;
                }
            }

            // ---- GEMM2 (kt = w) ----
            {
                short8_t a2[2];
                #pragma unroll
                for (int kit = 0; kit < 2; ++kit)
                    a2[kit] = *(const short8_t*)&sa2s[(16 * w + l15) * 72 + kit * 32 + 8 * q];
                __builtin_amdgcn_s_setprio(1);
                #pragma unroll
                for (int ct = 0; ct < 8; ++ct)
                    #pragma unroll
                    for (int kit = 0; kit < 2; ++kit) {
                        const unsigned short* bp = &xsN[(ct * 16 + l15) * 76 + kit * 32 + 8 * q];
                        short4_t b0 = *(const short4_t*)bp;
                        short4_t b1 = *(const short4_t*)(bp + 4);
                        short8_t bb;
                        bb[0] = b0[0]; bb[1] = b0[1]; bb[2] = b0[2]; bb[3] = b0[3];
                        bb[4] = b1[0]; bb[5] = b1[1]; bb[6] = b1[2]; bb[7] = b1[3];
                        acc2[ct] = __builtin_amdgcn_mfma_f32_16x16x32_bf16(a2[kit], bb, acc2[ct], 0, 0, 0);
                    }
                __builtin_amdgcn_s_setprio(0);
            }
            bar_lds();                          // B2: reuse guard
        }
    }

    // ---- epilogue: vlad partials + in-reg S reduce ----
    float* vp = vlad_part + ((size_t)blk8 * N + n) * (size_t)(K * C);
    #pragma unroll
    for (int ct = 0; ct < 8; ++ct)
        #pragma unroll
        for (int r = 0; r < 4; ++r)
            vp[(16 * w + 4 * q + r) * C + ct * 16 + l15] = acc2[ct][r];

    #pragma unroll
    for (int i = 0; i < 16; ++i) {
        Sreg[i] += __shfl_xor(Sreg[i], 1);
        Sreg[i] += __shfl_xor(Sreg[i], 2);
        Sreg[i] += __shfl_xor(Sreg[i], 4);
        Sreg[i] += __shfl_xor(Sreg[i], 8);
    }
    if (l15 == 0) {
        #pragma unroll
        for (int i = 0; i < 16; ++i)
            Sb2[w * 64 + 16 * (i >> 2) + 4 * q + (i & 3)] = Sreg[i];
    }
    __syncthreads();
    if (tid < 64)
        Spart[((size_t)blk8 * N + n) * K + tid] =
            Sb2[tid] + Sb2[64 + tid] + Sb2[128 + tid] + Sb2[192 + tid];
}

// ---------------------------------------------------------------------------
// Post 1: 512 blocks (n x 8 k-rows). Reduce 8 partials, subtract W*S,
// intra-norm (c); 32-lane shuffle reduce; atomicAdd ss2 partial.
// ---------------------------------------------------------------------------
__global__ __launch_bounds__(256) void k_post1(
    const float* __restrict__ vlad_part, const float* __restrict__ W,
    const float* __restrict__ Spart, float* __restrict__ out,
    float* __restrict__ ss2acc)
{
    __shared__ float red[8];
    const int tid = threadIdx.x;
    const int n  = blockIdx.x >> 3;
    const int kq = blockIdx.x & 7;
    const int kl = tid >> 5;           // 0..7
    const int ci = tid & 31;           // 0..31
    const int k  = kq * 8 + kl;
    const int c0 = ci * 4;

    float Sk = 0.f;
    #pragma unroll
    for (int ch = 0; ch < NCH2; ++ch) Sk += Spart[(size_t)(ch * N + n) * K + k];

    float v[4];
    #pragma unroll
    for (int l = 0; l < 4; ++l) v[l] = 0.f;
    #pragma unroll
    for (int ch = 0; ch < NCH2; ++ch) {
        const float* vp = vlad_part + ((size_t)(ch * N + n) * K + k) * C + c0;
        float4 a = *(const float4*)&vp[0];
        v[0] += a.x; v[1] += a.y; v[2] += a.z; v[3] += a.w;
    }

    float ss = 0.f;
    #pragma unroll
    for (int l = 0; l < 4; ++l) {
        float val = v[l] - W[(size_t)(c0 + l) * K + k] * Sk;
        v[l] = val;
        ss = fmaf(val, val, ss);
    }
    ss += __shfl_xor(ss, 1);
    ss += __shfl_xor(ss, 2);
    ss += __shfl_xor(ss, 4);
    ss += __shfl_xor(ss, 8);
    ss += __shfl_xor(ss, 16);
    const float inv1 = 1.0f / fmaxf(sqrtf(ss), EPS);
    float ss2 = 0.f;
    #pragma unroll
    for (int l = 0; l < 4; ++l) { v[l] *= inv1; ss2 = fmaf(v[l], v[l], ss2); }
    ss2 += __shfl_xor(ss2, 1);
    ss2 += __shfl_xor(ss2, 2);
    ss2 += __shfl_xor(ss2, 4);
    ss2 += __shfl_xor(ss2, 8);
    ss2 += __shfl_xor(ss2, 16);
    if (ci == 0) red[kl] = ss2;
    __syncthreads();
    if (tid == 0) {
        float t = 0.f;
        #pragma unroll
        for (int i = 0; i < 8; ++i) t += red[i];
        atomicAdd(&ss2acc[n], t);
    }

    float* op = out + (size_t)n * K * C + (size_t)k * C + c0;
    *(float4*)&op[0] = (float4){v[0], v[1], v[2], v[3]};
}

// ---------------------------------------------------------------------------
// Post 2: global L2 rescale in place. grid = N*4.
// ---------------------------------------------------------------------------
__global__ __launch_bounds__(256) void k_post2(
    float* __restrict__ out, const float* __restrict__ ss2acc)
{
    const int n   = blockIdx.x >> 2;
    const int seg = blockIdx.x & 3;
    const float inv2 = 1.0f / fmaxf(sqrtf(ss2acc[n]), EPS);
    float* p = out + (size_t)n * K * C + (size_t)seg * 2048 + (size_t)threadIdx.x * 8;
    float4 a = *(const float4*)&p[0];
    float4 b = *(const float4*)&p[4];
    a.x *= inv2; a.y *= inv2; a.z *= inv2; a.w *= inv2;
    b.x *= inv2; b.y *= inv2; b.z *= inv2; b.w *= inv2;
    *(float4*)&p[0] = a;
    *(float4*)&p[4] = b;
}

// ---------------------------------------------------------------------------
extern "C" void kernel_launch(void* const* d_in, const int* in_sizes, int n_in,
                              void* d_out, int out_size, void* d_ws, size_t ws_size,
                              hipStream_t stream)
{
    const float* x    = (const float*)d_in[0];
    const float* W    = (const float*)d_in[1];
    const float* bias = (const float*)d_in[2];

    float* out_vlad   = (float*)d_out;                       // N*K*C
    float* out_logits = (float*)d_out + (size_t)N * K * C;   // N*K*P

    unsigned short* wnT = (unsigned short*)d_ws;                          // 16 KiB
    float* ss2acc       = (float*)((char*)d_ws + 16384);                  // 256 B
    float* Spart        = (float*)((char*)d_ws + 32768);                  // 128 KiB
    float* vlad_part    = (float*)((char*)d_ws + 32768 + 131072);         // 16 MiB

    k_prep<<<dim3(1), dim3(256), 0, stream>>>(W, wnT, ss2acc);
    k_fused<<<dim3(N * NCH2), dim3(256), 0, stream>>>(
        x, wnT, bias, out_logits, vlad_part, Spart);
    k_post1<<<dim3(N * 8), dim3(256), 0, stream>>>(vlad_part, W, Spart, out_vlad, ss2acc);
    k_post2<<<dim3(N * 4), dim3(256), 0, stream>>>(out_vlad, ss2acc);
}

// Round 10
// 269.827 us; speedup vs baseline: 1.0138x; 1.0138x over previous
//
#include <hip/hip_runtime.h>
#include <math.h>

#define ALPHA 50.0f
#define EPS 1e-12f

constexpr int N = 64, C = 128, P = 4096, K = 64;
constexpr int NCH2 = 8;           // partial groups (one per block per n)

typedef short short8_t __attribute__((ext_vector_type(8)));
typedef short short4_t __attribute__((ext_vector_type(4)));
typedef float f4 __attribute__((ext_vector_type(4)));
typedef unsigned int u32x4 __attribute__((ext_vector_type(4)));
typedef unsigned int u32x2 __attribute__((ext_vector_type(2)));

__device__ __forceinline__ unsigned short f2bf(float f) {
    union { float f; unsigned u; } v; v.f = f;
    unsigned r = (v.u + 0x7FFFu + ((v.u >> 16) & 1u)) >> 16;   // RNE
    return (unsigned short)r;
}

// packed f32x2 -> bf16x2 (RNE), single VALU op
__device__ __forceinline__ unsigned cvtpk(float lo, float hi) {
    unsigned r;
    asm("v_cvt_pk_bf16_f32 %0, %1, %2" : "=v"(r) : "v"(lo), "v"(hi));
    return r;
}

// __syncthreads() minus the vmcnt(0) drain: LDS-visibility barrier only.
__device__ __forceinline__ void bar_lds() {
    asm volatile("s_waitcnt lgkmcnt(0)" ::: "memory");
    __builtin_amdgcn_s_barrier();
}

// ---------------------------------------------------------------------------
// Prep: wnT[k][c] = bf16(W[c][k]/max(||W[:,k]||,eps)), one block; also zeroes
// the ss2 accumulator.
// ---------------------------------------------------------------------------
__global__ __launch_bounds__(256) void k_prep(
    const float* __restrict__ W, unsigned short* __restrict__ wnT,
    float* __restrict__ ss2acc)
{
    __shared__ float Wl[C * 65];
    __shared__ float red[256];
    __shared__ float cinv[K];
    const int tid = threadIdx.x;
    if (tid < K) ss2acc[tid] = 0.f;
    for (int idx = tid; idx < C * K; idx += 256) {
        int c = idx >> 6, k = idx & 63;
        Wl[c * 65 + k] = W[idx];
    }
    __syncthreads();
    {   // column sum-of-squares, tree order identical to rd8's prologue
        const int k = tid & 63, part = tid >> 6;
        float s = 0.f;
        #pragma unroll
        for (int i = 0; i < 32; ++i) {
            float v = Wl[(part * 32 + i) * 65 + k];
            s = fmaf(v, v, s);
        }
        red[tid] = s;
    }
    __syncthreads();
    if (tid < K)
        cinv[tid] = 1.0f / fmaxf(
            sqrtf(red[tid] + red[64 + tid] + red[128 + tid] + red[192 + tid]), EPS);
    __syncthreads();
    for (int idx = tid; idx < K * C; idx += 256) {
        int k = idx >> 7, c = idx & 127;
        wnT[idx] = f2bf(Wl[c * 65 + k] * cinv[k]);
    }
}

// ---------------------------------------------------------------------------
// Fused, wave-autonomous (rd8 skeleton) + stream fixes:
//  - prologue: af frags from L2-hot bf16 wnT (no W read, no barriers)
//  - 2-deep x prefetch (vA/vB; issue ch+2 when buffer dies)
//  - logits staged in LDS (lgs), stored cooperatively post-B1 as full-line
//    float4 bursts WITH nontemporal hint (rd9 dropped NT -> logits allocated
//    in L2/L3, evicted x, FETCH +54 MB = +27 us; this restores NT)
// ---------------------------------------------------------------------------
__global__ __launch_bounds__(256, 2) void k_fused(
    const float* __restrict__ x, const unsigned short* __restrict__ wnT,
    const float* __restrict__ bias, float* __restrict__ logits,
    float* __restrict__ vlad_part, float* __restrict__ Spart)
{
    __shared__ __align__(16) char smem[64512];
    unsigned short* xsT  = (unsigned short*)smem;            // [4 w][16 px][136 c] bf16, 17408 B
    unsigned short* xsN  = (unsigned short*)(smem + 17408);  // [128 c][76 px] bf16, 19456 B
    unsigned short* sa2s = (unsigned short*)(smem + 36864);  // [64 k][72 px] bf16, 9216 B
    float*          lgs  = (float*)(smem + 46080);           // [64 k][68 px] f32, 17408 B
    float*          Sb2  = (float*)(smem + 63488);           // [4][64] f32, 1024 B

    const int tid  = threadIdx.x;
    const int n    = blockIdx.x >> 3;
    const int blk8 = blockIdx.x & 7;
    const int pbase = blk8 * 512;

    const int w = tid >> 6, lane = tid & 63;
    const int q = lane >> 4, l15 = lane & 15;
    const int c2 = lane >> 2, px4 = lane & 3;    // staging roles

    // per-lane global base: c = 8*c2 + j rows, px = 16w + 4*px4 (+i)
    const float* xw = x + (size_t)n * C * P + pbase + 16 * w + 4 * px4 + (size_t)(8 * c2) * P;
    float4 vA[8], vB[8];
    short8_t af[4][4];      // A-frags for ALL 4 k-tiles x 4 c-steps (64 VGPR)
    float bzv[16];

    // ---- prologue: no barriers. 2-deep x prefetch + wnT frags + bias ----
    #pragma unroll
    for (int j = 0; j < 8; ++j) vA[j] = *(const float4*)&xw[(size_t)j * P];
    #pragma unroll
    for (int j = 0; j < 8; ++j) vB[j] = *(const float4*)&xw[(size_t)j * P + 64];
    #pragma unroll
    for (int kt = 0; kt < 4; ++kt) {
        #pragma unroll
        for (int s = 0; s < 4; ++s)
            af[kt][s] = *(const short8_t*)&wnT[(16 * kt + l15) * 128 + s * 32 + 8 * q];
        #pragma unroll
        for (int r = 0; r < 4; ++r)
            bzv[4 * kt + r] = bias[16 * kt + 4 * q + r] * ALPHA;
    }

    f4 acc2[8];
    #pragma unroll
    for (int ct = 0; ct < 8; ++ct) acc2[ct] = (f4){0.f, 0.f, 0.f, 0.f};
    float Sreg[16];
    #pragma unroll
    for (int i = 0; i < 16; ++i) Sreg[i] = 0.f;

    unsigned short* xsTw = xsT + w * 2176;   // own slice, 16 rows x 136 shorts

    for (int ch2 = 0; ch2 < 8; ch2 += 2) {
        #pragma unroll
        for (int ph = 0; ph < 2; ++ph) {
            const int ch = ch2 + ph;
            float4 (&vcur)[8] = ph ? vB : vA;
            const float* vf = (const float*)vcur;

            // ---- in-wave ssq + invs (no LDS) ----
            float pss[4] = {0.f, 0.f, 0.f, 0.f};
            #pragma unroll
            for (int j = 0; j < 8; ++j)
                #pragma unroll
                for (int i = 0; i < 4; ++i)
                    pss[i] = fmaf(vf[j * 4 + i], vf[j * 4 + i], pss[i]);
            #pragma unroll
            for (int i = 0; i < 4; ++i) {
                pss[i] += __shfl_xor(pss[i], 4);
                pss[i] += __shfl_xor(pss[i], 8);
                pss[i] += __shfl_xor(pss[i], 16);
                pss[i] += __shfl_xor(pss[i], 32);
            }
            float iv4[4];
            #pragma unroll
            for (int i = 0; i < 4; ++i) iv4[i] = 1.0f / fmaxf(sqrtf(pss[i]), EPS);

            // ---- stage own xsT slice (XOR-swizzled) + shared xsN ----
            #pragma unroll
            for (int i = 0; i < 4; ++i) {
                u32x4 t;
                #pragma unroll
                for (int jj = 0; jj < 4; ++jj)
                    t[jj] = cvtpk(vf[(2 * jj) * 4 + i], vf[(2 * jj + 1) * 4 + i]);
                const int row = 4 * px4 + i;
                *(u32x4*)&xsTw[row * 136 + 8 * (c2 ^ (row & 7))] = t;
            }
            #pragma unroll
            for (int j = 0; j < 8; ++j) {
                u32x2 t2;
                t2[0] = cvtpk(vf[j * 4 + 0], vf[j * 4 + 1]);
                t2[1] = cvtpk(vf[j * 4 + 2], vf[j * 4 + 3]);
                *(u32x2*)&xsN[(8 * c2 + j) * 76 + 16 * w + 4 * px4] = t2;
            }
            // ---- vcur dead: issue ch+2 loads (2 chunks of latency cover) ----
            if (ch + 2 < 8) {
                #pragma unroll
                for (int j = 0; j < 8; ++j)
                    vcur[j] = *(const float4*)&xw[(size_t)j * P + (ch + 2) * 64];
            }
            asm volatile("s_waitcnt lgkmcnt(0)" ::: "memory");  // own-slice w->r order
            __builtin_amdgcn_sched_barrier(0);                  // rule-18 hardening

            // ---- GEMM1 from own slice: 4 B-reads total, A in regs ----
            f4 acc1[4];
            #pragma unroll
            for (int t = 0; t < 4; ++t) acc1[t] = (f4){0.f, 0.f, 0.f, 0.f};
            __builtin_amdgcn_s_setprio(1);
            #pragma unroll
            for (int s = 0; s < 4; ++s) {
                short8_t bf = *(const short8_t*)&xsTw[l15 * 136 + 8 * ((4 * s + q) ^ (l15 & 7))];
                #pragma unroll
                for (int kt = 0; kt < 4; ++kt)
                    acc1[kt] = __builtin_amdgcn_mfma_f32_16x16x32_bf16(af[kt][s], bf, acc1[kt], 0, 0, 0);
            }
            __builtin_amdgcn_s_setprio(0);

            // ---- in-register softmax; logits -> lgs (LDS), not global ----
            const float s0 = __shfl(iv4[0], l15 >> 2);
            const float s1 = __shfl(iv4[1], l15 >> 2);
            const float s2 = __shfl(iv4[2], l15 >> 2);
            const float s3 = __shfl(iv4[3], l15 >> 2);
            const int li = l15 & 3;
            const float myiv = (li == 0) ? s0 : (li == 1) ? s1 : (li == 2) ? s2 : s3;

            float ev[16];
            float dl = 0.f;
            #pragma unroll
            for (int kt = 0; kt < 4; ++kt)
                #pragma unroll
                for (int r = 0; r < 4; ++r) {
                    const float lv = acc1[kt][r] * myiv;
                    lgs[(16 * kt + 4 * q + r) * 68 + 16 * w + l15] = lv;
                    const float e = __expf(fmaf(lv, ALPHA, bzv[4 * kt + r]));
                    ev[4 * kt + r] = e;
                    dl += e;
                }
            dl += __shfl_xor(dl, 16);
            dl += __shfl_xor(dl, 32);
            const float rf = 1.0f / dl;
            const float sc = rf * myiv;
            #pragma unroll
            for (int kt = 0; kt < 4; ++kt)
                #pragma unroll
                for (int r = 0; r < 4; ++r) {
                    const float e = ev[4 * kt + r];
                    Sreg[4 * kt + r] += e * rf;
                    sa2s[(16 * kt + 4 * q + r) * 72 + 16 * w + l15] = f2bf(e * sc);
                }
            bar_lds();                          // B1: sa2s + xsN + lgs visible

            // ---- cooperative logits store: full-line float4 NT writes ----
            {
                float* lgp = logits + (size_t)n * K * P + pbase + ch * 64;
                #pragma unroll
                for (int jj = 0; jj < 4; ++jj) {
                    const int k = 16 * w + 4 * jj + (lane >> 4);
                    const f4 t = *(const f4*)&lgs[k * 68 + 4 * (lane & 15)];
                    __builtin_nontemporal_store(t, (f4*)&lgp[(size_t)k * P + 4 * (lane & 15)]);
                }
            }

            // ---- GEMM2 (kt = w) ----
            {
                short8_t a2[2];
                #pragma unroll
                for (int kit = 0; kit < 2; ++kit)
                    a2[kit] = *(const short8_t*)&sa2s[(16 * w + l15) * 72 + kit * 32 + 8 * q];
                __builtin_amdgcn_s_setprio(1);
                #pragma unroll
                for (int ct = 0; ct < 8; ++ct)
                    #pragma unroll
                    for (int kit = 0; kit < 2; ++kit) {
                        const unsigned short* bp = &xsN[(ct * 16 + l15) * 76 + kit * 32 + 8 * q];
                        short4_t b0 = *(const short4_t*)bp;
                        short4_t b1 = *(const short4_t*)(bp + 4);
                        short8_t bb;
                        bb[0] = b0[0]; bb[1] = b0[1]; bb[2] = b0[2]; bb[3] = b0[3];
                        bb[4] = b1[0]; bb[5] = b1[1]; bb[6] = b1[2]; bb[7] = b1[3];
                        acc2[ct] = __builtin_amdgcn_mfma_f32_16x16x32_bf16(a2[kit], bb, acc2[ct], 0, 0, 0);
                    }
                __builtin_amdgcn_s_setprio(0);
            }
            bar_lds();                          // B2: reuse guard
        }
    }

    // ---- epilogue: vlad partials + in-reg S reduce ----
    float* vp = vlad_part + ((size_t)blk8 * N + n) * (size_t)(K * C);
    #pragma unroll
    for (int ct = 0; ct < 8; ++ct)
        #pragma unroll
        for (int r = 0; r < 4; ++r)
            vp[(16 * w + 4 * q + r) * C + ct * 16 + l15] = acc2[ct][r];

    #pragma unroll
    for (int i = 0; i < 16; ++i) {
        Sreg[i] += __shfl_xor(Sreg[i], 1);
        Sreg[i] += __shfl_xor(Sreg[i], 2);
        Sreg[i] += __shfl_xor(Sreg[i], 4);
        Sreg[i] += __shfl_xor(Sreg[i], 8);
    }
    if (l15 == 0) {
        #pragma unroll
        for (int i = 0; i < 16; ++i)
            Sb2[w * 64 + 16 * (i >> 2) + 4 * q + (i & 3)] = Sreg[i];
    }
    __syncthreads();
    if (tid < 64)
        Spart[((size_t)blk8 * N + n) * K + tid] =
            Sb2[tid] + Sb2[64 + tid] + Sb2[128 + tid] + Sb2[192 + tid];
}

// ---------------------------------------------------------------------------
// Post 1: 512 blocks (n x 8 k-rows). Reduce 8 partials, subtract W*S,
// intra-norm (c); 32-lane shuffle reduce; atomicAdd ss2 partial.
// ---------------------------------------------------------------------------
__global__ __launch_bounds__(256) void k_post1(
    const float* __restrict__ vlad_part, const float* __restrict__ W,
    const float* __restrict__ Spart, float* __restrict__ out,
    float* __restrict__ ss2acc)
{
    __shared__ float red[8];
    const int tid = threadIdx.x;
    const int n  = blockIdx.x >> 3;
    const int kq = blockIdx.x & 7;
    const int kl = tid >> 5;           // 0..7
    const int ci = tid & 31;           // 0..31
    const int k  = kq * 8 + kl;
    const int c0 = ci * 4;

    float Sk = 0.f;
    #pragma unroll
    for (int ch = 0; ch < NCH2; ++ch) Sk += Spart[(size_t)(ch * N + n) * K + k];

    float v[4];
    #pragma unroll
    for (int l = 0; l < 4; ++l) v[l] = 0.f;
    #pragma unroll
    for (int ch = 0; ch < NCH2; ++ch) {
        const float* vp = vlad_part + ((size_t)(ch * N + n) * K + k) * C + c0;
        float4 a = *(const float4*)&vp[0];
        v[0] += a.x; v[1] += a.y; v[2] += a.z; v[3] += a.w;
    }

    float ss = 0.f;
    #pragma unroll
    for (int l = 0; l < 4; ++l) {
        float val = v[l] - W[(size_t)(c0 + l) * K + k] * Sk;
        v[l] = val;
        ss = fmaf(val, val, ss);
    }
    ss += __shfl_xor(ss, 1);
    ss += __shfl_xor(ss, 2);
    ss += __shfl_xor(ss, 4);
    ss += __shfl_xor(ss, 8);
    ss += __shfl_xor(ss, 16);
    const float inv1 = 1.0f / fmaxf(sqrtf(ss), EPS);
    float ss2 = 0.f;
    #pragma unroll
    for (int l = 0; l < 4; ++l) { v[l] *= inv1; ss2 = fmaf(v[l], v[l], ss2); }
    ss2 += __shfl_xor(ss2, 1);
    ss2 += __shfl_xor(ss2, 2);
    ss2 += __shfl_xor(ss2, 4);
    ss2 += __shfl_xor(ss2, 8);
    ss2 += __shfl_xor(ss2, 16);
    if (ci == 0) red[kl] = ss2;
    __syncthreads();
    if (tid == 0) {
        float t = 0.f;
        #pragma unroll
        for (int i = 0; i < 8; ++i) t += red[i];
        atomicAdd(&ss2acc[n], t);
    }

    float* op = out + (size_t)n * K * C + (size_t)k * C + c0;
    *(float4*)&op[0] = (float4){v[0], v[1], v[2], v[3]};
}

// ---------------------------------------------------------------------------
// Post 2: global L2 rescale in place. grid = N*4.
// ---------------------------------------------------------------------------
__global__ __launch_bounds__(256) void k_post2(
    float* __restrict__ out, const float* __restrict__ ss2acc)
{
    const int n   = blockIdx.x >> 2;
    const int seg = blockIdx.x & 3;
    const float inv2 = 1.0f / fmaxf(sqrtf(ss2acc[n]), EPS);
    float* p = out + (size_t)n * K * C + (size_t)seg * 2048 + (size_t)threadIdx.x * 8;
    float4 a = *(const float4*)&p[0];
    float4 b = *(const float4*)&p[4];
    a.x *= inv2; a.y *= inv2; a.z *= inv2; a.w *= inv2;
    b.x *= inv2; b.y *= inv2; b.z *= inv2; b.w *= inv2;
    *(float4*)&p[0] = a;
    *(float4*)&p[4] = b;
}

// ---------------------------------------------------------------------------
extern "C" void kernel_launch(void* const* d_in, const int* in_sizes, int n_in,
                              void* d_out, int out_size, void* d_ws, size_t ws_size,
                              hipStream_t stream)
{
    const float* x    = (const float*)d_in[0];
    const float* W    = (const float*)d_in[1];
    const float* bias = (const float*)d_in[2];

    float* out_vlad   = (float*)d_out;                       // N*K*C
    float* out_logits = (float*)d_out + (size_t)N * K * C;   // N*K*P

    unsigned short* wnT = (unsigned short*)d_ws;                          // 16 KiB
    float* ss2acc       = (float*)((char*)d_ws + 16384);                  // 256 B
    float* Spart        = (float*)((char*)d_ws + 32768);                  // 128 KiB
    float* vlad_part    = (float*)((char*)d_ws + 32768 + 131072);         // 16 MiB

    k_prep<<<dim3(1), dim3(256), 0, stream>>>(W, wnT, ss2acc);
    k_fused<<<dim3(N * NCH2), dim3(256), 0, stream>>>(
        x, wnT, bias, out_logits, vlad_part, Spart);
    k_post1<<<dim3(N * 8), dim3(256), 0, stream>>>(vlad_part, W, Spart, out_vlad, ss2acc);
    k_post2<<<dim3(N * 4), dim3(256), 0, stream>>>(out_vlad, ss2acc);
}

// Round 11
// 236.289 us; speedup vs baseline: 1.1577x; 1.1419x over previous
//
#include <hip/hip_runtime.h>
#include <math.h>

#define ALPHA 50.0f
#define EPS 1e-12f

constexpr int N = 64, C = 128, P = 4096, K = 64;
constexpr int NCH2 = 8;           // partial groups (one per block per n)

typedef short short8_t __attribute__((ext_vector_type(8)));
typedef short short4_t __attribute__((ext_vector_type(4)));
typedef float f4 __attribute__((ext_vector_type(4)));
typedef unsigned int u32x4 __attribute__((ext_vector_type(4)));
typedef unsigned int u32x2 __attribute__((ext_vector_type(2)));

__device__ __forceinline__ unsigned short f2bf(float f) {
    union { float f; unsigned u; } v; v.f = f;
    unsigned r = (v.u + 0x7FFFu + ((v.u >> 16) & 1u)) >> 16;   // RNE
    return (unsigned short)r;
}

// packed f32x2 -> bf16x2 (RNE), single VALU op
__device__ __forceinline__ unsigned cvtpk(float lo, float hi) {
    unsigned r;
    asm("v_cvt_pk_bf16_f32 %0, %1, %2" : "=v"(r) : "v"(lo), "v"(hi));
    return r;
}

// __syncthreads() minus the vmcnt(0) drain: LDS-visibility barrier only.
__device__ __forceinline__ void bar_lds() {
    asm volatile("s_waitcnt lgkmcnt(0)" ::: "memory");
    __builtin_amdgcn_s_barrier();
}

// ---------------------------------------------------------------------------
// Fused, wave-autonomous (rd8 verbatim — measured best: 235.86 us headline,
// k_fused 85 us, FETCH 69 MB, WRITE 92 MB):
// 512 blocks x 256 threads. Block = (n, 512-px strip), 8 chunks of 64 px;
// wave w owns px sub-group [16w,16w+16). Two barriers per chunk.
// Logits: 16 scattered NT dword stores/lane — KEEP: rd9 (cached f4) and
// rd10 (f4+NT) both raised FETCH (123/104 vs 69) by evicting x from L3.
// ---------------------------------------------------------------------------
__global__ __launch_bounds__(256, 2) void k_fused(
    const float* __restrict__ x, const float* __restrict__ W,
    const float* __restrict__ bias, float* __restrict__ logits,
    float* __restrict__ vlad_part, float* __restrict__ Spart,
    float* __restrict__ ss2acc)
{
    __shared__ __align__(16) char smem[47616];
    unsigned short* xsT  = (unsigned short*)smem;            // [4 w][16 px][136 c] bf16, 17408 B
    unsigned short* xsN  = (unsigned short*)(smem + 17408);  // [128 c][76 px] bf16, 19456 B
    unsigned short* sa2s = (unsigned short*)(smem + 36864);  // [64 k][72 px] bf16, 9216 B
    float*          biass= (float*)(smem + 46080);           // 64 f
    float*          Sb2  = (float*)(smem + 46336);           // [4][64] f32 (epilogue) / red[256] (prologue)
    float*          red  = Sb2;
    float*          cinv = (float*)(smem + 47360);           // 64 f
    float*          Wl   = (float*)smem;                     // prologue: [128][68] f32 = 34816 B

    const int tid  = threadIdx.x;
    const int n    = blockIdx.x >> 3;
    const int blk8 = blockIdx.x & 7;
    const int pbase = blk8 * 512;

    const int w = tid >> 6, lane = tid & 63;
    const int q = lane >> 4, l15 = lane & 15;
    const int c2 = lane >> 2, px4 = lane & 3;    // staging roles: c' 0..15, px-quad 0..3

    if (blockIdx.x == 0 && tid < 64) ss2acc[tid] = 0.f;   // k_post1 accumulator
    if (tid < K) biass[tid] = bias[tid] * ALPHA;

    // per-lane global base: c = 8*c2 + j rows, px = 16w + 4*px4 (+i)
    const float* xw = x + (size_t)n * C * P + pbase + 16 * w + 4 * px4 + (size_t)(8 * c2) * P;
    float4 va[8];
    short8_t af[4][4];      // A-frags for ALL 4 k-tiles x 4 c-steps (64 VGPR)
    float bzv[16];

    // ---- prologue: Wn fragments (all k-tiles) + chunk-0 x prefetch ----
    {
        float4 wv[8];
        #pragma unroll
        for (int it = 0; it < 8; ++it)
            wv[it] = *(const float4*)&W[(size_t)(tid + it * 256) * 4];
        #pragma unroll
        for (int j = 0; j < 8; ++j) va[j] = *(const float4*)&xw[(size_t)j * P];
        #pragma unroll
        for (int it = 0; it < 8; ++it) {
            const int idx4 = tid + it * 256;          // float4 index into W[C][K]
            *(float4*)&Wl[(idx4 >> 4) * 68 + (idx4 & 15) * 4] = wv[it];
        }
        bar_lds();
        {   // column sum-of-squares (order-identical to rd4)
            const int k = tid & 63, part = tid >> 6;
            float s = 0.f;
            #pragma unroll
            for (int i = 0; i < 32; ++i) {
                float v = Wl[(part * 32 + i) * 68 + k];
                s = fmaf(v, v, s);
            }
            red[tid] = s;
        }
        bar_lds();
        if (tid < 64)
            cinv[tid] = 1.0f / fmaxf(
                sqrtf(red[tid] + red[64 + tid] + red[128 + tid] + red[192 + tid]), EPS);
        bar_lds();
        #pragma unroll
        for (int kt = 0; kt < 4; ++kt) {
            const float cv = cinv[16 * kt + l15];
            #pragma unroll
            for (int s = 0; s < 4; ++s)
                #pragma unroll
                for (int j = 0; j < 8; ++j)
                    af[kt][s][j] = (short)f2bf(
                        Wl[(s * 32 + 8 * q + j) * 68 + 16 * kt + l15] * cv);
            #pragma unroll
            for (int r = 0; r < 4; ++r) bzv[4 * kt + r] = biass[16 * kt + 4 * q + r];
        }
        bar_lds();   // drain before staging(0) overwrites Wl
    }

    f4 acc2[8];
    #pragma unroll
    for (int ct = 0; ct < 8; ++ct) acc2[ct] = (f4){0.f, 0.f, 0.f, 0.f};
    float Sreg[16];
    #pragma unroll
    for (int i = 0; i < 16; ++i) Sreg[i] = 0.f;

    unsigned short* xsTw = xsT + w * 2176;   // own slice, 16 rows x 136 shorts

    for (int ch = 0; ch < 8; ++ch) {
        const float* vf = (const float*)va;

        // ---- in-wave ssq + invs (no LDS) ----
        float pss[4] = {0.f, 0.f, 0.f, 0.f};
        #pragma unroll
        for (int j = 0; j < 8; ++j)
            #pragma unroll
            for (int i = 0; i < 4; ++i)
                pss[i] = fmaf(vf[j * 4 + i], vf[j * 4 + i], pss[i]);
        #pragma unroll
        for (int i = 0; i < 4; ++i) {
            pss[i] += __shfl_xor(pss[i], 4);
            pss[i] += __shfl_xor(pss[i], 8);
            pss[i] += __shfl_xor(pss[i], 16);
            pss[i] += __shfl_xor(pss[i], 32);
        }
        float iv4[4];
        #pragma unroll
        for (int i = 0; i < 4; ++i) iv4[i] = 1.0f / fmaxf(sqrtf(pss[i]), EPS);

        // ---- stage own xsT slice (XOR-swizzled 16B blocks) + shared xsN ----
        #pragma unroll
        for (int i = 0; i < 4; ++i) {
            u32x4 t;
            #pragma unroll
            for (int jj = 0; jj < 4; ++jj)
                t[jj] = cvtpk(vf[(2 * jj) * 4 + i], vf[(2 * jj + 1) * 4 + i]);
            const int row = 4 * px4 + i;
            *(u32x4*)&xsTw[row * 136 + 8 * (c2 ^ (row & 7))] = t;
        }
        #pragma unroll
        for (int j = 0; j < 8; ++j) {
            u32x2 t2;
            t2[0] = cvtpk(vf[j * 4 + 0], vf[j * 4 + 1]);
            t2[1] = cvtpk(vf[j * 4 + 2], vf[j * 4 + 3]);
            *(u32x2*)&xsN[(8 * c2 + j) * 76 + 16 * w + 4 * px4] = t2;
        }
        if (ch < 7) {   // next-chunk loads: in flight under GEMM1+softmax+GEMM2
            #pragma unroll
            for (int j = 0; j < 8; ++j)
                va[j] = *(const float4*)&xw[(size_t)j * P + (ch + 1) * 64];
        }
        asm volatile("s_waitcnt lgkmcnt(0)" ::: "memory");  // own-slice w->r order
        __builtin_amdgcn_sched_barrier(0);                  // rule-18 hardening

        // ---- GEMM1 from own slice: 4 B-reads total, A in regs ----
        f4 acc1[4];
        #pragma unroll
        for (int t = 0; t < 4; ++t) acc1[t] = (f4){0.f, 0.f, 0.f, 0.f};
        __builtin_amdgcn_s_setprio(1);
        #pragma unroll
        for (int s = 0; s < 4; ++s) {
            short8_t bf = *(const short8_t*)&xsTw[l15 * 136 + 8 * ((4 * s + q) ^ (l15 & 7))];
            #pragma unroll
            for (int kt = 0; kt < 4; ++kt)
                acc1[kt] = __builtin_amdgcn_mfma_f32_16x16x32_bf16(af[kt][s], bf, acc1[kt], 0, 0, 0);
        }
        __builtin_amdgcn_s_setprio(0);

        // ---- fully in-register softmax ----
        const float s0 = __shfl(iv4[0], l15 >> 2);
        const float s1 = __shfl(iv4[1], l15 >> 2);
        const float s2 = __shfl(iv4[2], l15 >> 2);
        const float s3 = __shfl(iv4[3], l15 >> 2);
        const int li = l15 & 3;
        const float myiv = (li == 0) ? s0 : (li == 1) ? s1 : (li == 2) ? s2 : s3;

        float* lgp = logits + (size_t)n * K * P + pbase + ch * 64 + 16 * w + l15;
        float ev[16];
        float dl = 0.f;
        #pragma unroll
        for (int kt = 0; kt < 4; ++kt)
            #pragma unroll
            for (int r = 0; r < 4; ++r) {
                const float lv = acc1[kt][r] * myiv;
                __builtin_nontemporal_store(lv, &lgp[(size_t)(16 * kt + 4 * q + r) * P]);
                const float e = __expf(fmaf(lv, ALPHA, bzv[4 * kt + r]));
                ev[4 * kt + r] = e;
                dl += e;
            }
        dl += __shfl_xor(dl, 16);
        dl += __shfl_xor(dl, 32);
        const float rf = 1.0f / dl;
        const float sc = rf * myiv;
        #pragma unroll
        for (int kt = 0; kt < 4; ++kt)
            #pragma unroll
            for (int r = 0; r < 4; ++r) {
                const float e = ev[4 * kt + r];
                Sreg[4 * kt + r] += e * rf;
                sa2s[(16 * kt + 4 * q + r) * 72 + 16 * w + l15] = f2bf(e * sc);
            }
        bar_lds();                              // B1: sa2s + xsN visible

        // ---- GEMM2 (kt = w) ----
        {
            short8_t a2[2];
            #pragma unroll
            for (int kit = 0; kit < 2; ++kit)
                a2[kit] = *(const short8_t*)&sa2s[(16 * w + l15) * 72 + kit * 32 + 8 * q];
            __builtin_amdgcn_s_setprio(1);
            #pragma unroll
            for (int ct = 0; ct < 8; ++ct)
                #pragma unroll
                for (int kit = 0; kit < 2; ++kit) {
                    const unsigned short* bp = &xsN[(ct * 16 + l15) * 76 + kit * 32 + 8 * q];
                    short4_t b0 = *(const short4_t*)bp;
                    short4_t b1 = *(const short4_t*)(bp + 4);
                    short8_t bb;
                    bb[0] = b0[0]; bb[1] = b0[1]; bb[2] = b0[2]; bb[3] = b0[3];
                    bb[4] = b1[0]; bb[5] = b1[1]; bb[6] = b1[2]; bb[7] = b1[3];
                    acc2[ct] = __builtin_amdgcn_mfma_f32_16x16x32_bf16(a2[kit], bb, acc2[ct], 0, 0, 0);
                }
            __builtin_amdgcn_s_setprio(0);
        }
        bar_lds();                              // B2: reuse guard
    }

    // ---- epilogue: vlad partials + in-reg S reduce ----
    float* vp = vlad_part + ((size_t)blk8 * N + n) * (size_t)(K * C);
    #pragma unroll
    for (int ct = 0; ct < 8; ++ct)
        #pragma unroll
        for (int r = 0; r < 4; ++r)
            vp[(16 * w + 4 * q + r) * C + ct * 16 + l15] = acc2[ct][r];

    #pragma unroll
    for (int i = 0; i < 16; ++i) {
        Sreg[i] += __shfl_xor(Sreg[i], 1);
        Sreg[i] += __shfl_xor(Sreg[i], 2);
        Sreg[i] += __shfl_xor(Sreg[i], 4);
        Sreg[i] += __shfl_xor(Sreg[i], 8);
    }
    if (l15 == 0) {
        #pragma unroll
        for (int i = 0; i < 16; ++i)
            Sb2[w * 64 + 16 * (i >> 2) + 4 * q + (i & 3)] = Sreg[i];
    }
    __syncthreads();
    if (tid < 64)
        Spart[((size_t)blk8 * N + n) * K + tid] =
            Sb2[tid] + Sb2[64 + tid] + Sb2[128 + tid] + Sb2[192 + tid];
}

// ---------------------------------------------------------------------------
// Post 1: 512 blocks (n x 8 k-rows). Reduce 8 partials, subtract W*S,
// intra-norm (c); 32-lane shuffle reduce; atomicAdd ss2 partial.
// ---------------------------------------------------------------------------
__global__ __launch_bounds__(256) void k_post1(
    const float* __restrict__ vlad_part, const float* __restrict__ W,
    const float* __restrict__ Spart, float* __restrict__ out,
    float* __restrict__ ss2acc)
{
    __shared__ float red[8];
    const int tid = threadIdx.x;
    const int n  = blockIdx.x >> 3;
    const int kq = blockIdx.x & 7;
    const int kl = tid >> 5;           // 0..7
    const int ci = tid & 31;           // 0..31
    const int k  = kq * 8 + kl;
    const int c0 = ci * 4;

    float Sk = 0.f;
    #pragma unroll
    for (int ch = 0; ch < NCH2; ++ch) Sk += Spart[(size_t)(ch * N + n) * K + k];

    float v[4];
    #pragma unroll
    for (int l = 0; l < 4; ++l) v[l] = 0.f;
    #pragma unroll
    for (int ch = 0; ch < NCH2; ++ch) {
        const float* vp = vlad_part + ((size_t)(ch * N + n) * K + k) * C + c0;
        float4 a = *(const float4*)&vp[0];
        v[0] += a.x; v[1] += a.y; v[2] += a.z; v[3] += a.w;
    }

    float ss = 0.f;
    #pragma unroll
    for (int l = 0; l < 4; ++l) {
        float val = v[l] - W[(size_t)(c0 + l) * K + k] * Sk;
        v[l] = val;
        ss = fmaf(val, val, ss);
    }
    ss += __shfl_xor(ss, 1);
    ss += __shfl_xor(ss, 2);
    ss += __shfl_xor(ss, 4);
    ss += __shfl_xor(ss, 8);
    ss += __shfl_xor(ss, 16);
    const float inv1 = 1.0f / fmaxf(sqrtf(ss), EPS);
    float ss2 = 0.f;
    #pragma unroll
    for (int l = 0; l < 4; ++l) { v[l] *= inv1; ss2 = fmaf(v[l], v[l], ss2); }
    ss2 += __shfl_xor(ss2, 1);
    ss2 += __shfl_xor(ss2, 2);
    ss2 += __shfl_xor(ss2, 4);
    ss2 += __shfl_xor(ss2, 8);
    ss2 += __shfl_xor(ss2, 16);
    if (ci == 0) red[kl] = ss2;
    __syncthreads();
    if (tid == 0) {
        float t = 0.f;
        #pragma unroll
        for (int i = 0; i < 8; ++i) t += red[i];
        atomicAdd(&ss2acc[n], t);
    }

    float* op = out + (size_t)n * K * C + (size_t)k * C + c0;
    *(float4*)&op[0] = (float4){v[0], v[1], v[2], v[3]};
}

// ---------------------------------------------------------------------------
// Post 2: global L2 rescale in place. grid = N*4.
// ---------------------------------------------------------------------------
__global__ __launch_bounds__(256) void k_post2(
    float* __restrict__ out, const float* __restrict__ ss2acc)
{
    const int n   = blockIdx.x >> 2;
    const int seg = blockIdx.x & 3;
    const float inv2 = 1.0f / fmaxf(sqrtf(ss2acc[n]), EPS);
    float* p = out + (size_t)n * K * C + (size_t)seg * 2048 + (size_t)threadIdx.x * 8;
    float4 a = *(const float4*)&p[0];
    float4 b = *(const float4*)&p[4];
    a.x *= inv2; a.y *= inv2; a.z *= inv2; a.w *= inv2;
    b.x *= inv2; b.y *= inv2; b.z *= inv2; b.w *= inv2;
    *(float4*)&p[0] = a;
    *(float4*)&p[4] = b;
}

// ---------------------------------------------------------------------------
extern "C" void kernel_launch(void* const* d_in, const int* in_sizes, int n_in,
                              void* d_out, int out_size, void* d_ws, size_t ws_size,
                              hipStream_t stream)
{
    const float* x    = (const float*)d_in[0];
    const float* W    = (const float*)d_in[1];
    const float* bias = (const float*)d_in[2];

    float* out_vlad   = (float*)d_out;                       // N*K*C
    float* out_logits = (float*)d_out + (size_t)N * K * C;   // N*K*P

    float* ss2acc     = (float*)((char*)d_ws + 16384);                  // 256 B
    float* Spart      = (float*)((char*)d_ws + 32768);                  // 128 KiB
    float* vlad_part  = (float*)((char*)d_ws + 32768 + 131072);         // 16 MiB

    k_fused<<<dim3(N * NCH2), dim3(256), 0, stream>>>(
        x, W, bias, out_logits, vlad_part, Spart, ss2acc);
    k_post1<<<dim3(N * 8), dim3(256), 0, stream>>>(vlad_part, W, Spart, out_vlad, ss2acc);
    k_post2<<<dim3(N * 4), dim3(256), 0, stream>>>(out_vlad, ss2acc);
}